// Round 9
// baseline (225.487 us; speedup 1.0000x reference)
//
#include <hip/hip_runtime.h>
#include <hip/hip_bf16.h>
#include <math.h>

// Problem constants (fixed by setup_inputs)
#define S_   64
#define H_   32
#define D_   128
#define KVH_ 8
#define G_   4
#define BS_  16
#define MB_  128
#define LMAX_ 2048
#define PART_ 128
#define MAXP_ (LMAX_ / PART_)          // 16

#define SCALE_ 0.08838834764831845f  // 1/sqrt(128)
#define MINIT_ -1.0e30f              // finite "neg-inf": corr=exp(m-mn) never NaN

// Locality-first flash-decode partial kernel.
// WG = (seq, 128-token partition), 256 threads = 8 groups of 32 lanes,
// group g = KV HEAD g. All 8 groups walk the SAME pages together, reading
// adjacent 8KB kvh-slices -> each page is one contiguous 64KB K burst +
// 64KB V burst (vs 8 scattered 8KB fetches when kvh is split across items).
// Each group keeps the full online-softmax state for its 4 GQA heads over
// all 8 pages: no LDS, no barriers, partial written directly.
// Grid = 16x64 = 1024 WGs = exactly 4 WGs/CU residency at VGPR<=128.
__global__ __launch_bounds__(256)
void pa_partial(const float* __restrict__ q,
                const float* __restrict__ kc,
                const float* __restrict__ vc,
                const int* __restrict__ bt,
                const int* __restrict__ cl,
                float* __restrict__ ws)
{
    const int part = blockIdx.x;
    const int s    = blockIdx.y;

    const int len = cl[s];
    const int t0  = part * PART_;
    if (t0 >= len) return;

    const int tid = threadIdx.x;
    const int kvh = tid >> 5;    // group = kv head 0..7
    const int l32 = tid & 31;    // float4 slice of D

    // Q fragments: this kvh's 4 GQA heads
    float4 qv[G_];
#pragma unroll
    for (int g = 0; g < G_; ++g)
        qv[g] = *(const float4*)(q + ((size_t)(s * H_ + kvh * G_ + g)) * D_ + l32 * 4);

    float  m[G_], l[G_];
    float4 acc[G_];
#pragma unroll
    for (int g = 0; g < G_; ++g) {
        m[g] = MINIT_; l[g] = 0.f;
        acc[g] = make_float4(0.f, 0.f, 0.f, 0.f);
    }

    const int* btr = bt + s * MB_;
    const int npages = min(PART_ / BS_, ((len - t0) + BS_ - 1) >> 4);

    for (int p = 0; p < npages; ++p) {
        const int bid = btr[(t0 >> 4) + p];
        const float* kp = kc + (size_t)bid * (KVH_ * BS_ * D_)
                             + (size_t)kvh * (BS_ * D_) + l32 * 4;
        const float* vp = vc + (size_t)bid * (KVH_ * BS_ * D_)
                             + (size_t)kvh * (BS_ * D_) + l32 * 4;
        const int tpage = t0 + p * BS_;

#pragma unroll
        for (int b = 0; b < 4; ++b) {
            // Burst 4 K rows + 4 V rows (any row of a valid page exists;
            // only scores are masked).
            float4 k4[4], v4[4];
#pragma unroll
            for (int i = 0; i < 4; ++i) {
                k4[i] = *(const float4*)(kp + (size_t)(b * 4 + i) * D_);
                v4[i] = *(const float4*)(vp + (size_t)(b * 4 + i) * D_);
            }

            // Partial dots: 16 independent values.
            float sc[4][G_];
#pragma unroll
            for (int i = 0; i < 4; ++i)
#pragma unroll
                for (int g = 0; g < G_; ++g)
                    sc[i][g] = qv[g].x * k4[i].x + qv[g].y * k4[i].y +
                               qv[g].z * k4[i].z + qv[g].w * k4[i].w;

            // Butterfly reduce across the 32-lane group; 16 chains pipeline.
#pragma unroll
            for (int off = 16; off; off >>= 1)
#pragma unroll
                for (int i = 0; i < 4; ++i)
#pragma unroll
                    for (int g = 0; g < G_; ++g)
                        sc[i][g] += __shfl_xor(sc[i][g], off, 32);

            // Scale + mask tokens beyond len.
#pragma unroll
            for (int i = 0; i < 4; ++i) {
                const bool valid = (tpage + b * 4 + i) < len;
#pragma unroll
                for (int g = 0; g < G_; ++g)
                    sc[i][g] = valid ? sc[i][g] * SCALE_ : -INFINITY;
            }

            // Online-softmax update (m finite always; masked p -> 0).
#pragma unroll
            for (int g = 0; g < G_; ++g) {
                const float smax = fmaxf(fmaxf(sc[0][g], sc[1][g]),
                                         fmaxf(sc[2][g], sc[3][g]));
                const float mn   = fmaxf(m[g], smax);
                const float corr = __expf(m[g] - mn);
                const float p0 = __expf(sc[0][g] - mn);
                const float p1 = __expf(sc[1][g] - mn);
                const float p2 = __expf(sc[2][g] - mn);
                const float p3 = __expf(sc[3][g] - mn);
                l[g] = l[g] * corr + ((p0 + p1) + (p2 + p3));
                acc[g].x = acc[g].x * corr + p0 * v4[0].x + p1 * v4[1].x + p2 * v4[2].x + p3 * v4[3].x;
                acc[g].y = acc[g].y * corr + p0 * v4[0].y + p1 * v4[1].y + p2 * v4[2].y + p3 * v4[3].y;
                acc[g].z = acc[g].z * corr + p0 * v4[0].z + p1 * v4[1].z + p2 * v4[2].z + p3 * v4[3].z;
                acc[g].w = acc[g].w * corr + p0 * v4[0].w + p1 * v4[1].w + p2 * v4[2].w + p3 * v4[3].w;
                m[g] = mn;
            }
        }
    }

    // Write this group's partial directly: (m,l) identical across the 32
    // lanes after the butterfly; acc is the lane's float4 d-slice.
    // ws layout: [S_][KVH_][MAXP_][G_][130] floats (same as combine expects).
#pragma unroll
    for (int g = 0; g < G_; ++g) {
        float* pb = ws + (((size_t)(s * KVH_ + kvh) * MAXP_ + part) * G_ + g) * 130;
        if (l32 == 0) { pb[0] = m[g]; pb[1] = l[g]; }
        *(float4*)(pb + 2 + l32 * 4) = acc[g];
    }
}

// Combine kernel: one WG (128 threads) per (seq, head); reduce over partitions.
__global__ __launch_bounds__(128)
void pa_combine(const float* __restrict__ ws,
                const int* __restrict__ cl,
                float* __restrict__ out)
{
    const int h = blockIdx.x;   // 0..31
    const int s = blockIdx.y;   // 0..63
    const int kvh = h >> 2;
    const int g   = h & 3;
    const int d   = threadIdx.x;

    const int len = cl[s];
    const int np  = (len + PART_ - 1) / PART_;

    const float* base = ws + ((size_t)(s * KVH_ + kvh) * MAXP_) * (G_ * 130) + (size_t)g * 130;

    float M = MINIT_;
    for (int p = 0; p < np; ++p) M = fmaxf(M, base[(size_t)p * (G_ * 130)]);

    float L = 0.f, val = 0.f;
    for (int p = 0; p < np; ++p) {
        const float* pb = base + (size_t)p * (G_ * 130);
        const float w = __expf(pb[0] - M);
        L   += w * pb[1];
        val += w * pb[2 + d];
    }
    out[((size_t)s * H_ + h) * D_ + d] = val / L;
}

extern "C" void kernel_launch(void* const* d_in, const int* in_sizes, int n_in,
                              void* d_out, int out_size, void* d_ws, size_t ws_size,
                              hipStream_t stream)
{
    const float* q  = (const float*)d_in[0];
    const float* kc = (const float*)d_in[1];
    const float* vc = (const float*)d_in[2];
    const int*   bt = (const int*)d_in[3];
    const int*   cl = (const int*)d_in[4];
    float* out = (float*)d_out;
    float* ws  = (float*)d_ws;

    // ws layout: [S_][KVH_][MAXP_][G_][130] floats = 17.04 MB (proven size).
    dim3 grid1(MAXP_, S_);
    pa_partial<<<grid1, 256, 0, stream>>>(q, kc, vc, bt, cl, ws);

    dim3 grid2(H_, S_);
    pa_combine<<<grid2, 128, 0, stream>>>(ws, cl, out);
}